// Round 1
// baseline (1236.025 us; speedup 1.0000x reference)
//
#include <hip/hip_runtime.h>
#include <hip/hip_bf16.h>

#define N_NODES 50000
#define N_EDGES 600000
#define D 128

constexpr float AVG_D_LOG = 1.6094379124341003f;  // log(5)
constexpr float EPS_V = 1e-5f;

// workspace layout (float elements)
#define SUM_OFF   0
#define SQ_OFF    6400000
#define MAX_OFF   12800000
#define MIN_OFF   19200000
#define DEG_OFF   25600000
#define WS_TOT    25650000

typedef __attribute__((ext_vector_type(8))) short bf16x8;
typedef __attribute__((ext_vector_type(4))) float f32x4;
typedef __attribute__((ext_vector_type(4))) short s16x4;

__device__ __forceinline__ short f2b(float f) {
    unsigned u = __builtin_bit_cast(unsigned, f);
    u += 0x7fffu + ((u >> 16) & 1u);   // RNE
    return (short)(u >> 16);
}

// ---------------------------------------------------------------- init
__global__ __launch_bounds__(256) void init_kernel(unsigned* __restrict__ ws) {
    long i = (long)blockIdx.x * 256 + threadIdx.x;
    if (i >= WS_TOT) return;
    unsigned v = 0u;
    if (i >= MIN_OFF && i < DEG_OFF) v = 0x7f800000u;  // min init = +inf
    ws[i] = v;                                          // others 0 (= 0.0f)
}

// ---------------------------------------------------------------- degree
__global__ __launch_bounds__(256) void deg_kernel(const int* __restrict__ edst,
                                                  float* __restrict__ deg) {
    int e = blockIdx.x * 256 + threadIdx.x;
    if (e < N_EDGES) atomicAdd(&deg[edst[e]], 1.0f);
}

// ---------------------------------------------------------------- edge MLP + scatter stats
// one block = 128 edges, full 128 output channels, K=256 (src||dst)
__global__ __launch_bounds__(256) void edge_kernel(
    const float* __restrict__ h, const int* __restrict__ esrc, const int* __restrict__ edst,
    const float* __restrict__ Wpre, const float* __restrict__ bpre,
    float* __restrict__ sum, float* __restrict__ sumsq,
    unsigned* __restrict__ maxb, unsigned* __restrict__ minb)
{
    __shared__ __align__(16) short As[128][72];   // [edge][k] bf16, +8 pad
    __shared__ __align__(16) short Bs[128][72];   // [n][k] bf16 (W_pre transposed)
    __shared__ int ssrc[128];
    __shared__ int sdst[128];

    const int tid = threadIdx.x;
    const int bm = blockIdx.x * 128;
    if (tid < 128) {
        int e = bm + tid;
        int ec = e < N_EDGES ? e : (N_EDGES - 1);
        ssrc[tid] = esrc[ec];
        sdst[tid] = edst[ec];
    }
    __syncthreads();

    const int lane = tid & 63, wv = tid >> 6;
    const int lm = lane & 15, quad = lane >> 4;

    f32x4 acc[2][8];
#pragma unroll
    for (int a = 0; a < 2; a++)
#pragma unroll
        for (int b = 0; b < 8; b++) acc[a][b] = (f32x4){0.f, 0.f, 0.f, 0.f};

#pragma unroll
    for (int kc = 0; kc < 4; kc++) {           // K chunks of 64: src[0:64],src[64:128],dst[0:64],dst[64:128]
        __syncthreads();
        const int half = (kc & 1) * 64;
        // stage A: 128 edges x 64 ch
#pragma unroll
        for (int t = 0; t < 8; t++) {
            int q = tid + t * 256;
            int m = q >> 4, seg = q & 15;
            int node = (kc < 2) ? ssrc[m] : sdst[m];
            const float4 v = *(const float4*)(h + (long)node * D + half + seg * 4);
            s16x4 w; w.x = f2b(v.x); w.y = f2b(v.y); w.z = f2b(v.z); w.w = f2b(v.w);
            *(s16x4*)&As[m][seg * 4] = w;
        }
        // stage B: W_pre rows [kc*64, +64), transposed into Bs[n][k]
#pragma unroll
        for (int t = 0; t < 8; t++) {
            int q = tid + t * 256;
            int kl = q >> 5, n4 = (q & 31) * 4;
            const float4 v = *(const float4*)(Wpre + (long)(kc * 64 + kl) * D + n4);
            Bs[n4 + 0][kl] = f2b(v.x);
            Bs[n4 + 1][kl] = f2b(v.y);
            Bs[n4 + 2][kl] = f2b(v.z);
            Bs[n4 + 3][kl] = f2b(v.w);
        }
        __syncthreads();
#pragma unroll
        for (int ks = 0; ks < 2; ks++) {
            const int ko = ks * 32 + quad * 8;
            bf16x8 af0 = *(const bf16x8*)&As[wv * 32 + lm][ko];
            bf16x8 af1 = *(const bf16x8*)&As[wv * 32 + 16 + lm][ko];
#pragma unroll
            for (int ct = 0; ct < 8; ct++) {
                bf16x8 bf = *(const bf16x8*)&Bs[ct * 16 + lm][ko];
                acc[0][ct] = __builtin_amdgcn_mfma_f32_16x16x32_bf16(af0, bf, acc[0][ct], 0, 0, 0);
                acc[1][ct] = __builtin_amdgcn_mfma_f32_16x16x32_bf16(af1, bf, acc[1][ct], 0, 0, 0);
            }
        }
    }

    // epilogue: bias + relu + scatter atomics
    float bias[8];
#pragma unroll
    for (int ct = 0; ct < 8; ct++) bias[ct] = bpre[ct * 16 + lm];

#pragma unroll
    for (int rt = 0; rt < 2; rt++) {
#pragma unroll
        for (int i = 0; i < 4; i++) {
            int rloc = wv * 32 + rt * 16 + quad * 4 + i;
            int eg = bm + rloc;
            if (eg >= N_EDGES) continue;
            long base = (long)sdst[rloc] * D;
#pragma unroll
            for (int ct = 0; ct < 8; ct++) {
                int col = ct * 16 + lm;
                float v = acc[rt][ct][i] + bias[ct];
                v = v > 0.f ? v : 0.f;
                atomicAdd(&sum[base + col], v);
                atomicAdd(&sumsq[base + col], v * v);
                atomicMax(&maxb[base + col], __float_as_uint(v));
                atomicMin(&minb[base + col], __float_as_uint(v));
            }
        }
    }
}

// ---------------------------------------------------------------- fused post + mix per node
// one block = 128 nodes. post: x[1664] @ W_post -> hp[128]; mix: hp @ W_mix; residual.
__global__ __launch_bounds__(256) void node_kernel(
    const float* __restrict__ h,
    const float* __restrict__ Wpost, const float* __restrict__ bpost,
    const float* __restrict__ Wmix, const float* __restrict__ bmix,
    const float* __restrict__ sum, const float* __restrict__ sumsq,
    const unsigned* __restrict__ maxb, const unsigned* __restrict__ minb,
    const float* __restrict__ deg, float* __restrict__ out)
{
    __shared__ __align__(16) short As[128][72];
    __shared__ __align__(16) short Bs[128][72];
    __shared__ float sInv[128], sAmp[128], sAtt[128];

    const int tid = threadIdx.x;
    const int bn = blockIdx.x * 128;
    if (tid < 128) {
        int n = bn + tid;
        int nc = n < N_NODES ? n : (N_NODES - 1);
        float d = deg[nc];
        float ld = logf(d + 1.0f);
        sInv[tid] = 1.0f / d;
        sAmp[tid] = ld * (1.0f / AVG_D_LOG);
        sAtt[tid] = AVG_D_LOG / ld;
    }
    __syncthreads();

    const int lane = tid & 63, wv = tid >> 6;
    const int lm = lane & 15, quad = lane >> 4;

    f32x4 acc[2][8];
#pragma unroll
    for (int a = 0; a < 2; a++)
#pragma unroll
        for (int b = 0; b < 8; b++) acc[a][b] = (f32x4){0.f, 0.f, 0.f, 0.f};

    // ---- post GEMM: K = 1664 = 26 chunks of 64
    for (int c = 0; c < 26; c++) {
        __syncthreads();
        const int r = c >> 1;            // region 0=h, 1..12 = agg*scaler
        const int half = (c & 1) * 64;
        // stage A: synthesize x[:, c*64 : c*64+64]
#pragma unroll
        for (int t = 0; t < 8; t++) {
            int q = tid + t * 256;
            int m = q >> 4, seg = q & 15;
            int n = bn + m;
            int nc = n < N_NODES ? n : (N_NODES - 1);
            int ch = half + seg * 4;
            long idx = (long)nc * D + ch;
            float4 v;
            if (r == 0) {
                v = *(const float4*)(h + idx);
            } else {
                int a = (r - 1) & 3, s = (r - 1) >> 2;
                float inv = sInv[m];
                if (a == 0) {               // mean
                    float4 sv = *(const float4*)(sum + idx);
                    v.x = sv.x * inv; v.y = sv.y * inv; v.z = sv.z * inv; v.w = sv.w * inv;
                } else if (a == 1) {        // max
                    uint4 b = *(const uint4*)(maxb + idx);
                    v.x = __uint_as_float(b.x); v.y = __uint_as_float(b.y);
                    v.z = __uint_as_float(b.z); v.w = __uint_as_float(b.w);
                } else if (a == 2) {        // min
                    uint4 b = *(const uint4*)(minb + idx);
                    v.x = __uint_as_float(b.x); v.y = __uint_as_float(b.y);
                    v.z = __uint_as_float(b.z); v.w = __uint_as_float(b.w);
                } else {                    // std
                    float4 sv = *(const float4*)(sum + idx);
                    float4 qv = *(const float4*)(sumsq + idx);
                    float mx_ = sv.x * inv, my_ = sv.y * inv, mz_ = sv.z * inv, mw_ = sv.w * inv;
                    float vx = qv.x * inv - mx_ * mx_; vx = vx > 0.f ? vx : 0.f;
                    float vy = qv.y * inv - my_ * my_; vy = vy > 0.f ? vy : 0.f;
                    float vz = qv.z * inv - mz_ * mz_; vz = vz > 0.f ? vz : 0.f;
                    float vw = qv.w * inv - mw_ * mw_; vw = vw > 0.f ? vw : 0.f;
                    v.x = sqrtf(vx + EPS_V); v.y = sqrtf(vy + EPS_V);
                    v.z = sqrtf(vz + EPS_V); v.w = sqrtf(vw + EPS_V);
                }
                float sc = (s == 0) ? 1.0f : (s == 1 ? sAmp[m] : sAtt[m]);
                v.x *= sc; v.y *= sc; v.z *= sc; v.w *= sc;
            }
            s16x4 w; w.x = f2b(v.x); w.y = f2b(v.y); w.z = f2b(v.z); w.w = f2b(v.w);
            *(s16x4*)&As[m][seg * 4] = w;
        }
        // stage B: W_post rows [c*64, +64) transposed
#pragma unroll
        for (int t = 0; t < 8; t++) {
            int q = tid + t * 256;
            int kl = q >> 5, n4 = (q & 31) * 4;
            const float4 v = *(const float4*)(Wpost + (long)(c * 64 + kl) * D + n4);
            Bs[n4 + 0][kl] = f2b(v.x);
            Bs[n4 + 1][kl] = f2b(v.y);
            Bs[n4 + 2][kl] = f2b(v.z);
            Bs[n4 + 3][kl] = f2b(v.w);
        }
        __syncthreads();
#pragma unroll
        for (int ks = 0; ks < 2; ks++) {
            const int ko = ks * 32 + quad * 8;
            bf16x8 af0 = *(const bf16x8*)&As[wv * 32 + lm][ko];
            bf16x8 af1 = *(const bf16x8*)&As[wv * 32 + 16 + lm][ko];
#pragma unroll
            for (int ct = 0; ct < 8; ct++) {
                bf16x8 bf = *(const bf16x8*)&Bs[ct * 16 + lm][ko];
                acc[0][ct] = __builtin_amdgcn_mfma_f32_16x16x32_bf16(af0, bf, acc[0][ct], 0, 0, 0);
                acc[1][ct] = __builtin_amdgcn_mfma_f32_16x16x32_bf16(af1, bf, acc[1][ct], 0, 0, 0);
            }
        }
    }

    // hp = relu(acc + b_post)  (in place)
    {
        float biasP[8];
#pragma unroll
        for (int ct = 0; ct < 8; ct++) biasP[ct] = bpost[ct * 16 + lm];
#pragma unroll
        for (int rt = 0; rt < 2; rt++)
#pragma unroll
            for (int ct = 0; ct < 8; ct++)
#pragma unroll
                for (int i = 0; i < 4; i++) {
                    float v = acc[rt][ct][i] + biasP[ct];
                    acc[rt][ct][i] = v > 0.f ? v : 0.f;
                }
    }

    // ---- mix GEMM: K = 128 = 2 chunks of 64; A comes from hp (= acc) registers
    f32x4 acc2[2][8];
#pragma unroll
    for (int a = 0; a < 2; a++)
#pragma unroll
        for (int b = 0; b < 8; b++) acc2[a][b] = (f32x4){0.f, 0.f, 0.f, 0.f};

#pragma unroll
    for (int kc = 0; kc < 2; kc++) {
        __syncthreads();
        // stage A: hp cols [kc*64, +64) from C-layout registers
#pragma unroll
        for (int ctl = 0; ctl < 4; ctl++) {
            int ct = kc * 4 + ctl;
#pragma unroll
            for (int rt = 0; rt < 2; rt++)
#pragma unroll
                for (int i = 0; i < 4; i++) {
                    int row = wv * 32 + rt * 16 + quad * 4 + i;
                    int colL = ctl * 16 + lm;
                    As[row][colL] = f2b(acc[rt][ct][i]);
                }
        }
        // stage B: W_mix rows [kc*64, +64) transposed
#pragma unroll
        for (int t = 0; t < 8; t++) {
            int q = tid + t * 256;
            int kl = q >> 5, n4 = (q & 31) * 4;
            const float4 v = *(const float4*)(Wmix + (long)(kc * 64 + kl) * D + n4);
            Bs[n4 + 0][kl] = f2b(v.x);
            Bs[n4 + 1][kl] = f2b(v.y);
            Bs[n4 + 2][kl] = f2b(v.z);
            Bs[n4 + 3][kl] = f2b(v.w);
        }
        __syncthreads();
#pragma unroll
        for (int ks = 0; ks < 2; ks++) {
            const int ko = ks * 32 + quad * 8;
            bf16x8 af0 = *(const bf16x8*)&As[wv * 32 + lm][ko];
            bf16x8 af1 = *(const bf16x8*)&As[wv * 32 + 16 + lm][ko];
#pragma unroll
            for (int ct = 0; ct < 8; ct++) {
                bf16x8 bf = *(const bf16x8*)&Bs[ct * 16 + lm][ko];
                acc2[0][ct] = __builtin_amdgcn_mfma_f32_16x16x32_bf16(af0, bf, acc2[0][ct], 0, 0, 0);
                acc2[1][ct] = __builtin_amdgcn_mfma_f32_16x16x32_bf16(af1, bf, acc2[1][ct], 0, 0, 0);
            }
        }
    }

    // epilogue: out = h + leaky_relu(acc2 + b_mix)
    float biasM[8];
#pragma unroll
    for (int ct = 0; ct < 8; ct++) biasM[ct] = bmix[ct * 16 + lm];
#pragma unroll
    for (int rt = 0; rt < 2; rt++) {
#pragma unroll
        for (int i = 0; i < 4; i++) {
            int row = wv * 32 + rt * 16 + quad * 4 + i;
            int n = bn + row;
            if (n >= N_NODES) continue;
#pragma unroll
            for (int ct = 0; ct < 8; ct++) {
                int col = ct * 16 + lm;
                float v = acc2[rt][ct][i] + biasM[ct];
                v = v > 0.f ? v : 0.01f * v;
                out[(long)n * D + col] = h[(long)n * D + col] + v;
            }
        }
    }
}

extern "C" void kernel_launch(void* const* d_in, const int* in_sizes, int n_in,
                              void* d_out, int out_size, void* d_ws, size_t ws_size,
                              hipStream_t stream) {
    const float* h     = (const float*)d_in[0];
    const int*   esrc  = (const int*)d_in[1];
    const int*   edst  = (const int*)d_in[2];
    const float* Wpre  = (const float*)d_in[3];
    const float* bpre  = (const float*)d_in[4];
    const float* Wpost = (const float*)d_in[5];
    const float* bpost = (const float*)d_in[6];
    const float* Wmix  = (const float*)d_in[7];
    const float* bmix  = (const float*)d_in[8];
    float* out = (float*)d_out;
    float* ws  = (float*)d_ws;

    float*    sum   = ws + SUM_OFF;
    float*    sumsq = ws + SQ_OFF;
    unsigned* maxb  = (unsigned*)(ws + MAX_OFF);
    unsigned* minb  = (unsigned*)(ws + MIN_OFF);
    float*    deg   = ws + DEG_OFF;

    init_kernel<<<(WS_TOT + 255) / 256, 256, 0, stream>>>((unsigned*)ws);
    deg_kernel<<<(N_EDGES + 255) / 256, 256, 0, stream>>>(edst, deg);
    edge_kernel<<<(N_EDGES + 127) / 128, 256, 0, stream>>>(h, esrc, edst, Wpre, bpre,
                                                           sum, sumsq, maxb, minb);
    node_kernel<<<(N_NODES + 127) / 128, 256, 0, stream>>>(h, Wpost, bpost, Wmix, bmix,
                                                           sum, sumsq, maxb, minb, deg, out);
}

// Round 2
// 465.369 us; speedup vs baseline: 2.6560x; 2.6560x over previous
//
#include <hip/hip_runtime.h>
#include <hip/hip_bf16.h>

#define N_NODES 50000
#define N_EDGES 600000
#define D 128
#define NB_SCAN 196  // ceil(50000/256)

constexpr float AVG_D_LOG = 1.6094379124341003f;  // log(5)
constexpr float EPS_V = 1e-5f;

// ---- workspace byte offsets (total ~221.2 MB)
#define EBUF_B   0ul          // bf16 [600000][128]  = 153,600,000
#define AGG_B    153600000ul  // bf16 [50000][512]   =  51,200,000  (mean|max|min|std)
#define HBF_B    204800000ul  // bf16 [50000][128]   =  12,800,000
#define WPRET_B  217600000ul  // bf16 [128][256]
#define WPOSTT_B 217665536ul  // bf16 [128][1664]
#define WMIXT_B  218091520ul  // bf16 [128][128]
#define DEGC_B   218124288ul  // int  [50000]
#define OFF_B    218324288ul  // int  [50016]
#define CUR_B    218524352ul  // int  [50000]
#define PERM_B   218724352ul  // int  [600000]
#define BSUM_B   221124352ul  // int  [256]

typedef __attribute__((ext_vector_type(8))) short bf16x8;
typedef __attribute__((ext_vector_type(4))) float f32x4;

__device__ __forceinline__ short f2b(float f) {
    unsigned u = __builtin_bit_cast(unsigned, f);
    u += 0x7fffu + ((u >> 16) & 1u);   // RNE
    return (short)(u >> 16);
}
__device__ __forceinline__ unsigned pk2(float a, float b) {
    return (unsigned)(unsigned short)f2b(a) | ((unsigned)(unsigned short)f2b(b) << 16);
}

// ---------------------------------------------------------------- prep: bf16 conversions + zeroing
__global__ __launch_bounds__(256) void prep_kernel(
    const float* __restrict__ h, const float* __restrict__ Wpre,
    const float* __restrict__ Wpost, const float* __restrict__ Wmix,
    short* __restrict__ hbf, short* __restrict__ wpreT,
    short* __restrict__ wpostT, short* __restrict__ wmixT,
    int* __restrict__ degc, int* __restrict__ cursor)
{
    long i = (long)blockIdx.x * 256 + threadIdx.x;
    if (i < 6400000) { hbf[i] = f2b(h[i]); return; }
    i -= 6400000;
    if (i < 32768) { int k = i >> 7, n = i & 127; wpreT[n * 256 + k] = f2b(Wpre[k * 128 + n]); return; }
    i -= 32768;
    if (i < 212992) { int k = i >> 7, n = i & 127; wpostT[n * 1664 + k] = f2b(Wpost[k * 128 + n]); return; }
    i -= 212992;
    if (i < 16384) { int k = i >> 7, n = i & 127; wmixT[n * 128 + k] = f2b(Wmix[k * 128 + n]); return; }
    i -= 16384;
    if (i < N_NODES) { degc[i] = 0; return; }
    i -= N_NODES;
    if (i < N_NODES) cursor[i] = 0;
}

// ---------------------------------------------------------------- degree histogram
__global__ __launch_bounds__(256) void hist_kernel(const int* __restrict__ edst, int* __restrict__ degc) {
    int e = blockIdx.x * 256 + threadIdx.x;
    if (e < N_EDGES) atomicAdd(&degc[edst[e]], 1);
}

// ---------------------------------------------------------------- scan (3 kernels)
__global__ __launch_bounds__(256) void scan1_kernel(const int* __restrict__ degc, int* __restrict__ bsum) {
    int n = blockIdx.x * 256 + threadIdx.x;
    int v = (n < N_NODES) ? degc[n] : 0;
#pragma unroll
    for (int o = 32; o > 0; o >>= 1) v += __shfl_down(v, o);
    __shared__ int w4[4];
    if ((threadIdx.x & 63) == 0) w4[threadIdx.x >> 6] = v;
    __syncthreads();
    if (threadIdx.x == 0) bsum[blockIdx.x] = w4[0] + w4[1] + w4[2] + w4[3];
}

__global__ void scan2_kernel(int* __restrict__ bsum, int* __restrict__ off) {
    if (threadIdx.x == 0 && blockIdx.x == 0) {
        int r = 0;
        for (int i = 0; i < NB_SCAN; i++) { int t = bsum[i]; bsum[i] = r; r += t; }
        off[N_NODES] = r;   // = 600000
    }
}

__global__ __launch_bounds__(256) void scan3_kernel(const int* __restrict__ degc,
                                                    const int* __restrict__ bsum, int* __restrict__ off) {
    __shared__ int sd[256];
    int tid = threadIdx.x;
    int n = blockIdx.x * 256 + tid;
    int v = (n < N_NODES) ? degc[n] : 0;
    sd[tid] = v;
    __syncthreads();
    for (int o = 1; o < 256; o <<= 1) {
        int t = (tid >= o) ? sd[tid - o] : 0;
        __syncthreads();
        sd[tid] += t;
        __syncthreads();
    }
    if (n < N_NODES) off[n] = sd[tid] - v + bsum[blockIdx.x];
}

// ---------------------------------------------------------------- scatter: perm[pos] = edge id (sorted by dst)
__global__ __launch_bounds__(256) void scatter_kernel(const int* __restrict__ edst, const int* __restrict__ off,
                                                      int* __restrict__ cursor, int* __restrict__ perm) {
    int e = blockIdx.x * 256 + threadIdx.x;
    if (e < N_EDGES) {
        int d = edst[e];
        int p = off[d] + atomicAdd(&cursor[d], 1);
        perm[p] = e;
    }
}

// ---------------------------------------------------------------- edge MLP -> ebuf (sorted, no atomics)
__global__ __launch_bounds__(256) void edge_kernel(
    const short* __restrict__ hbf, const int* __restrict__ esrc, const int* __restrict__ edst,
    const int* __restrict__ perm, const short* __restrict__ wpreT,
    const float* __restrict__ bpre, short* __restrict__ ebuf)
{
    __shared__ __align__(16) short As[128][72];   // [edge][k], +8 pad (row = 144B)
    __shared__ __align__(16) short Bs[128][72];   // [n][k]
    __shared__ int ssrc[128], sdst[128];

    const int tid = threadIdx.x;
    const int bm = blockIdx.x * 128;
    if (tid < 128) {
        int p = bm + tid; if (p >= N_EDGES) p = N_EDGES - 1;
        int e = perm[p];
        ssrc[tid] = esrc[e];
        sdst[tid] = edst[e];
    }
    __syncthreads();

    const int lane = tid & 63, wv = tid >> 6;
    const int lm = lane & 15, quad = lane >> 4;

    f32x4 acc[2][8];
#pragma unroll
    for (int a = 0; a < 2; a++)
#pragma unroll
        for (int b = 0; b < 8; b++) acc[a][b] = (f32x4){0.f, 0.f, 0.f, 0.f};

#pragma unroll
    for (int kc = 0; kc < 4; kc++) {   // src[0:64], src[64:128], dst[0:64], dst[64:128]
        __syncthreads();
        const int half = (kc & 1) * 64;
#pragma unroll
        for (int t = 0; t < 4; t++) {
            int q = tid + t * 256;
            int m = q >> 3, seg = q & 7;
            int node = (kc < 2) ? ssrc[m] : sdst[m];
            int4 v = *(const int4*)(hbf + (long)node * 128 + half + seg * 8);
            *(int4*)&As[m][seg * 8] = v;
        }
#pragma unroll
        for (int t = 0; t < 4; t++) {
            int q = tid + t * 256;
            int n = q >> 3, seg = q & 7;
            int4 v = *(const int4*)(wpreT + n * 256 + kc * 64 + seg * 8);
            *(int4*)&Bs[n][seg * 8] = v;
        }
        __syncthreads();
#pragma unroll
        for (int ks = 0; ks < 2; ks++) {
            const int ko = ks * 32 + quad * 8;
            bf16x8 a0 = *(const bf16x8*)&As[wv * 32 + lm][ko];
            bf16x8 a1 = *(const bf16x8*)&As[wv * 32 + 16 + lm][ko];
#pragma unroll
            for (int ct = 0; ct < 8; ct++) {
                bf16x8 b = *(const bf16x8*)&Bs[ct * 16 + lm][ko];
                // swapped operands: D = C^T -> lane holds row=edge(lm), 4 consecutive cols
                acc[0][ct] = __builtin_amdgcn_mfma_f32_16x16x32_bf16(b, a0, acc[0][ct], 0, 0, 0);
                acc[1][ct] = __builtin_amdgcn_mfma_f32_16x16x32_bf16(b, a1, acc[1][ct], 0, 0, 0);
            }
        }
    }

    // epilogue: bias + relu, pack 4 bf16, store 8B per (rt,ct); rows are sorted positions -> contiguous
#pragma unroll
    for (int rt = 0; rt < 2; rt++) {
        int el = wv * 32 + rt * 16 + lm;
        int p = bm + el;
        if (p >= N_EDGES) continue;
        short* dst = ebuf + (long)p * 128;
#pragma unroll
        for (int ct = 0; ct < 8; ct++) {
            float4 bv = *(const float4*)(bpre + ct * 16 + quad * 4);
            float v0 = acc[rt][ct][0] + bv.x; v0 = v0 > 0.f ? v0 : 0.f;
            float v1 = acc[rt][ct][1] + bv.y; v1 = v1 > 0.f ? v1 : 0.f;
            float v2 = acc[rt][ct][2] + bv.z; v2 = v2 > 0.f ? v2 : 0.f;
            float v3 = acc[rt][ct][3] + bv.w; v3 = v3 > 0.f ? v3 : 0.f;
            int2 pkd; pkd.x = (int)pk2(v0, v1); pkd.y = (int)pk2(v2, v3);
            *(int2*)(dst + ct * 16 + quad * 4) = pkd;
        }
    }
}

// ---------------------------------------------------------------- per-node stats: one wave per node
__global__ __launch_bounds__(256) void stats_kernel(
    const short* __restrict__ ebuf, const int* __restrict__ off, short* __restrict__ aggbf)
{
    const int wv = threadIdx.x >> 6, lane = threadIdx.x & 63;
    const int n = blockIdx.x * 4 + wv;           // grid 12500*4 == 50000 exactly
    const int s0 = off[n];
    const int s1 = off[n + 1];
    float sA = 0.f, sB = 0.f, qA = 0.f, qB = 0.f;
    float mxA = -1e30f, mxB = -1e30f, mnA = 1e30f, mnB = 1e30f;
    const unsigned* base = (const unsigned*)ebuf;
    for (int p = s0; p < s1; ++p) {
        unsigned u = base[(long)p * 64 + lane];
        float a = __uint_as_float(u << 16);
        float b = __uint_as_float(u & 0xffff0000u);
        sA += a; sB += b; qA += a * a; qB += b * b;
        mxA = fmaxf(mxA, a); mxB = fmaxf(mxB, b);
        mnA = fminf(mnA, a); mnB = fminf(mnB, b);
    }
    float inv = 1.0f / (float)(s1 - s0);         // deg >= 1 (self-loops)
    float mA = sA * inv, mB = sB * inv;
    float vA = qA * inv - mA * mA; vA = vA > 0.f ? vA : 0.f;
    float vB = qB * inv - mB * mB; vB = vB > 0.f ? vB : 0.f;
    float stA = sqrtf(vA + EPS_V), stB = sqrtf(vB + EPS_V);
    unsigned* ag = (unsigned*)(aggbf + (long)n * 512);
    ag[lane]       = pk2(mA, mB);    // mean
    ag[64 + lane]  = pk2(mxA, mxB);  // max
    ag[128 + lane] = pk2(mnA, mnB);  // min
    ag[192 + lane] = pk2(stA, stB);  // std
}

// ---------------------------------------------------------------- fused post + mix per node
__global__ __launch_bounds__(256) void node_kernel(
    const float* __restrict__ h, const short* __restrict__ hbf, const short* __restrict__ aggbf,
    const int* __restrict__ degc, const short* __restrict__ wpostT, const float* __restrict__ bpost,
    const short* __restrict__ wmixT, const float* __restrict__ bmix, float* __restrict__ out)
{
    __shared__ __align__(16) short As[128][72];
    __shared__ __align__(16) short Bs[128][72];
    __shared__ float sAmp[128], sAtt[128];

    const int tid = threadIdx.x;
    const int bn = blockIdx.x * 128;
    if (tid < 128) {
        int n = bn + tid; if (n >= N_NODES) n = N_NODES - 1;
        float d = (float)degc[n];
        float ld = logf(d + 1.0f);
        sAmp[tid] = ld * (1.0f / AVG_D_LOG);
        sAtt[tid] = AVG_D_LOG / ld;
    }
    __syncthreads();

    const int lane = tid & 63, wv = tid >> 6;
    const int lm = lane & 15, quad = lane >> 4;

    f32x4 acc[2][8];
#pragma unroll
    for (int a = 0; a < 2; a++)
#pragma unroll
        for (int b = 0; b < 8; b++) acc[a][b] = (f32x4){0.f, 0.f, 0.f, 0.f};

    // ---- post GEMM: K = 1664 = 26 chunks of 64
    for (int c = 0; c < 26; c++) {
        __syncthreads();
        const int r = c >> 1;
        const int half = (c & 1) * 64;
#pragma unroll
        for (int t = 0; t < 4; t++) {
            int q = tid + t * 256;
            int m = q >> 3, seg = q & 7;
            int n = bn + m; if (n >= N_NODES) n = N_NODES - 1;
            int4 v;
            if (r == 0) {
                v = *(const int4*)(hbf + (long)n * 128 + half + seg * 8);
            } else {
                int a = (r - 1) & 3, s = (r - 1) >> 2;
                v = *(const int4*)(aggbf + (long)n * 512 + a * 128 + half + seg * 8);
                if (s) {
                    float sc = (s == 1) ? sAmp[m] : sAtt[m];
                    unsigned* pu = (unsigned*)&v;
#pragma unroll
                    for (int j = 0; j < 4; j++) {
                        unsigned u = pu[j];
                        float a0 = __uint_as_float(u << 16) * sc;
                        float a1 = __uint_as_float(u & 0xffff0000u) * sc;
                        pu[j] = pk2(a0, a1);
                    }
                }
            }
            *(int4*)&As[m][seg * 8] = v;
        }
#pragma unroll
        for (int t = 0; t < 4; t++) {
            int q = tid + t * 256;
            int n = q >> 3, seg = q & 7;
            *(int4*)&Bs[n][seg * 8] = *(const int4*)(wpostT + n * 1664 + c * 64 + seg * 8);
        }
        __syncthreads();
#pragma unroll
        for (int ks = 0; ks < 2; ks++) {
            const int ko = ks * 32 + quad * 8;
            bf16x8 a0 = *(const bf16x8*)&As[wv * 32 + lm][ko];
            bf16x8 a1 = *(const bf16x8*)&As[wv * 32 + 16 + lm][ko];
#pragma unroll
            for (int ct = 0; ct < 8; ct++) {
                bf16x8 b = *(const bf16x8*)&Bs[ct * 16 + lm][ko];
                acc[0][ct] = __builtin_amdgcn_mfma_f32_16x16x32_bf16(b, a0, acc[0][ct], 0, 0, 0);
                acc[1][ct] = __builtin_amdgcn_mfma_f32_16x16x32_bf16(b, a1, acc[1][ct], 0, 0, 0);
            }
        }
    }

    // hp = relu(acc + b_post); lane holds node=wv*32+rt*16+lm, cols ct*16+quad*4..+3
#pragma unroll
    for (int rt = 0; rt < 2; rt++)
#pragma unroll
        for (int ct = 0; ct < 8; ct++) {
            float4 bv = *(const float4*)(bpost + ct * 16 + quad * 4);
            float v0 = acc[rt][ct][0] + bv.x; acc[rt][ct][0] = v0 > 0.f ? v0 : 0.f;
            float v1 = acc[rt][ct][1] + bv.y; acc[rt][ct][1] = v1 > 0.f ? v1 : 0.f;
            float v2 = acc[rt][ct][2] + bv.z; acc[rt][ct][2] = v2 > 0.f ? v2 : 0.f;
            float v3 = acc[rt][ct][3] + bv.w; acc[rt][ct][3] = v3 > 0.f ? v3 : 0.f;
        }

    // ---- mix GEMM: K = 128 = 2 chunks
    f32x4 acc2[2][8];
#pragma unroll
    for (int a = 0; a < 2; a++)
#pragma unroll
        for (int b = 0; b < 8; b++) acc2[a][b] = (f32x4){0.f, 0.f, 0.f, 0.f};

#pragma unroll
    for (int kc = 0; kc < 2; kc++) {
        __syncthreads();
        // restage hp cols [kc*64, +64) from registers (packed 8B writes)
#pragma unroll
        for (int ctl = 0; ctl < 4; ctl++) {
            int ct = kc * 4 + ctl;
#pragma unroll
            for (int rt = 0; rt < 2; rt++) {
                int row = wv * 32 + rt * 16 + lm;
                int col = ctl * 16 + quad * 4;
                int2 pkd;
                pkd.x = (int)pk2(acc[rt][ct][0], acc[rt][ct][1]);
                pkd.y = (int)pk2(acc[rt][ct][2], acc[rt][ct][3]);
                *(int2*)&As[row][col] = pkd;
            }
        }
#pragma unroll
        for (int t = 0; t < 4; t++) {
            int q = tid + t * 256;
            int n = q >> 3, seg = q & 7;
            *(int4*)&Bs[n][seg * 8] = *(const int4*)(wmixT + n * 128 + kc * 64 + seg * 8);
        }
        __syncthreads();
#pragma unroll
        for (int ks = 0; ks < 2; ks++) {
            const int ko = ks * 32 + quad * 8;
            bf16x8 a0 = *(const bf16x8*)&As[wv * 32 + lm][ko];
            bf16x8 a1 = *(const bf16x8*)&As[wv * 32 + 16 + lm][ko];
#pragma unroll
            for (int ct = 0; ct < 8; ct++) {
                bf16x8 b = *(const bf16x8*)&Bs[ct * 16 + lm][ko];
                acc2[0][ct] = __builtin_amdgcn_mfma_f32_16x16x32_bf16(b, a0, acc2[0][ct], 0, 0, 0);
                acc2[1][ct] = __builtin_amdgcn_mfma_f32_16x16x32_bf16(b, a1, acc2[1][ct], 0, 0, 0);
            }
        }
    }

    // epilogue: out = h + leaky_relu(acc2 + b_mix); float4 stores
#pragma unroll
    for (int rt = 0; rt < 2; rt++) {
        int row = wv * 32 + rt * 16 + lm;
        int n = bn + row;
        if (n >= N_NODES) continue;
#pragma unroll
        for (int ct = 0; ct < 8; ct++) {
            int col = ct * 16 + quad * 4;
            float4 bv = *(const float4*)(bmix + col);
            float4 hv = *(const float4*)(h + (long)n * 128 + col);
            float4 o;
            float v0 = acc2[rt][ct][0] + bv.x; v0 = v0 > 0.f ? v0 : 0.01f * v0; o.x = hv.x + v0;
            float v1 = acc2[rt][ct][1] + bv.y; v1 = v1 > 0.f ? v1 : 0.01f * v1; o.y = hv.y + v1;
            float v2 = acc2[rt][ct][2] + bv.z; v2 = v2 > 0.f ? v2 : 0.01f * v2; o.z = hv.z + v2;
            float v3 = acc2[rt][ct][3] + bv.w; v3 = v3 > 0.f ? v3 : 0.01f * v3; o.w = hv.w + v3;
            *(float4*)(out + (long)n * 128 + col) = o;
        }
    }
}

extern "C" void kernel_launch(void* const* d_in, const int* in_sizes, int n_in,
                              void* d_out, int out_size, void* d_ws, size_t ws_size,
                              hipStream_t stream) {
    const float* h     = (const float*)d_in[0];
    const int*   esrc  = (const int*)d_in[1];
    const int*   edst  = (const int*)d_in[2];
    const float* Wpre  = (const float*)d_in[3];
    const float* bpre  = (const float*)d_in[4];
    const float* Wpost = (const float*)d_in[5];
    const float* bpost = (const float*)d_in[6];
    const float* Wmix  = (const float*)d_in[7];
    const float* bmix  = (const float*)d_in[8];
    float* out = (float*)d_out;
    char* ws = (char*)d_ws;

    short* ebuf   = (short*)(ws + EBUF_B);
    short* aggbf  = (short*)(ws + AGG_B);
    short* hbf    = (short*)(ws + HBF_B);
    short* wpreT  = (short*)(ws + WPRET_B);
    short* wpostT = (short*)(ws + WPOSTT_B);
    short* wmixT  = (short*)(ws + WMIXT_B);
    int*   degc   = (int*)(ws + DEGC_B);
    int*   off    = (int*)(ws + OFF_B);
    int*   cursor = (int*)(ws + CUR_B);
    int*   perm   = (int*)(ws + PERM_B);
    int*   bsum   = (int*)(ws + BSUM_B);

    prep_kernel<<<26415, 256, 0, stream>>>(h, Wpre, Wpost, Wmix, hbf, wpreT, wpostT, wmixT, degc, cursor);
    hist_kernel<<<(N_EDGES + 255) / 256, 256, 0, stream>>>(edst, degc);
    scan1_kernel<<<NB_SCAN, 256, 0, stream>>>(degc, bsum);
    scan2_kernel<<<1, 64, 0, stream>>>(bsum, off);
    scan3_kernel<<<NB_SCAN, 256, 0, stream>>>(degc, bsum, off);
    scatter_kernel<<<(N_EDGES + 255) / 256, 256, 0, stream>>>(edst, off, cursor, perm);
    edge_kernel<<<(N_EDGES + 127) / 128, 256, 0, stream>>>(hbf, esrc, edst, perm, wpreT, bpre, ebuf);
    stats_kernel<<<N_NODES / 4, 256, 0, stream>>>(ebuf, off, aggbf);
    node_kernel<<<(N_NODES + 127) / 128, 256, 0, stream>>>(h, hbf, aggbf, degc, wpostT, bpost, wmixT, bmix, out);
}

// Round 3
// 294.954 us; speedup vs baseline: 4.1906x; 1.5778x over previous
//
#include <hip/hip_runtime.h>
#include <hip/hip_bf16.h>

#define N_NODES 50000
#define N_EDGES 600000
#define D 128
#define NB_SCAN 196  // ceil(50000/256)

constexpr float AVG_D_LOG = 1.6094379124341003f;  // log(5)
constexpr float EPS_V = 1e-5f;

// ---- workspace byte offsets (total ~93.1 MB)
#define PQ_B     0ul           // bf16 [50000][256]  P|Q rows     = 25,600,000
#define AGG_B    25600000ul    // bf16 [50000][512]  mean|max|min|std = 51,200,000
#define HBF_B    76800000ul    // bf16 [50000][128]
#define WPRET2_B 89600000ul    // bf16 [256][128]   (P cols | Q cols, [n][k])
#define WPOSTT_B 89665536ul    // bf16 [128][1664]
#define WMIXT_B  90091520ul    // bf16 [128][128]
#define DEGC_B   90124288ul    // int  [50000]
#define OFF_B    90324288ul    // int  [50016]
#define CUR_B    90524352ul    // int  [50000]
#define SRCS_B   90724352ul    // int  [600000]  src ids in dst-sorted order
#define BSUM_B   93124352ul    // int  [256]

typedef __attribute__((ext_vector_type(8))) short bf16x8;
typedef __attribute__((ext_vector_type(4))) float f32x4;

__device__ __forceinline__ short f2b(float f) {
    unsigned u = __builtin_bit_cast(unsigned, f);
    u += 0x7fffu + ((u >> 16) & 1u);   // RNE
    return (short)(u >> 16);
}
__device__ __forceinline__ unsigned pk2(float a, float b) {
    return (unsigned)(unsigned short)f2b(a) | ((unsigned)(unsigned short)f2b(b) << 16);
}
__device__ __forceinline__ float blo(unsigned u) { return __uint_as_float(u << 16); }
__device__ __forceinline__ float bhi(unsigned u) { return __uint_as_float(u & 0xffff0000u); }

// ---------------------------------------------------------------- prep
__global__ __launch_bounds__(256) void prep_kernel(
    const float* __restrict__ h, const float* __restrict__ Wpre,
    const float* __restrict__ Wpost, const float* __restrict__ Wmix,
    short* __restrict__ hbf, short* __restrict__ wpreT2,
    short* __restrict__ wpostT, short* __restrict__ wmixT,
    int* __restrict__ degc, int* __restrict__ cursor)
{
    long i = (long)blockIdx.x * 256 + threadIdx.x;
    if (i < 6400000) { hbf[i] = f2b(h[i]); return; }
    i -= 6400000;
    if (i < 32768) {  // wpreT2[n][k]: n<128 -> Wpre[k][n] (top); n>=128 -> Wpre[k+128][n-128]
        int n = i >> 7, k = i & 127;
        float v = (n < 128) ? Wpre[k * 128 + n] : Wpre[(k + 128) * 128 + (n - 128)];
        wpreT2[n * 128 + k] = f2b(v);
        return;
    }
    i -= 32768;
    if (i < 212992) { int k = i >> 7, n = i & 127; wpostT[n * 1664 + k] = f2b(Wpost[k * 128 + n]); return; }
    i -= 212992;
    if (i < 16384) { int k = i >> 7, n = i & 127; wmixT[n * 128 + k] = f2b(Wmix[k * 128 + n]); return; }
    i -= 16384;
    if (i < N_NODES) { degc[i] = 0; return; }
    i -= N_NODES;
    if (i < N_NODES) cursor[i] = 0;
}

// ---------------------------------------------------------------- degree histogram
__global__ __launch_bounds__(256) void hist_kernel(const int* __restrict__ edst, int* __restrict__ degc) {
    int e = blockIdx.x * 256 + threadIdx.x;
    if (e < N_EDGES) atomicAdd(&degc[edst[e]], 1);
}

// ---------------------------------------------------------------- scan
__global__ __launch_bounds__(256) void scan1_kernel(const int* __restrict__ degc, int* __restrict__ bsum) {
    int n = blockIdx.x * 256 + threadIdx.x;
    int v = (n < N_NODES) ? degc[n] : 0;
#pragma unroll
    for (int o = 32; o > 0; o >>= 1) v += __shfl_down(v, o);
    __shared__ int w4[4];
    if ((threadIdx.x & 63) == 0) w4[threadIdx.x >> 6] = v;
    __syncthreads();
    if (threadIdx.x == 0) bsum[blockIdx.x] = w4[0] + w4[1] + w4[2] + w4[3];
}

__global__ void scan2_kernel(int* __restrict__ bsum, int* __restrict__ off) {
    if (threadIdx.x == 0 && blockIdx.x == 0) {
        int r = 0;
        for (int i = 0; i < NB_SCAN; i++) { int t = bsum[i]; bsum[i] = r; r += t; }
        off[N_NODES] = r;
    }
}

__global__ __launch_bounds__(256) void scan3_kernel(const int* __restrict__ degc,
                                                    const int* __restrict__ bsum, int* __restrict__ off) {
    __shared__ int sd[256];
    int tid = threadIdx.x;
    int n = blockIdx.x * 256 + tid;
    int v = (n < N_NODES) ? degc[n] : 0;
    sd[tid] = v;
    __syncthreads();
    for (int o = 1; o < 256; o <<= 1) {
        int t = (tid >= o) ? sd[tid - o] : 0;
        __syncthreads();
        sd[tid] += t;
        __syncthreads();
    }
    if (n < N_NODES) off[n] = sd[tid] - v + bsum[blockIdx.x];
}

// ---------------------------------------------------------------- scatter srcs into dst-sorted order
__global__ __launch_bounds__(256) void scatter_kernel(const int* __restrict__ esrc, const int* __restrict__ edst,
                                                      const int* __restrict__ off, int* __restrict__ cursor,
                                                      int* __restrict__ srcs) {
    int e = blockIdx.x * 256 + threadIdx.x;
    if (e < N_EDGES) {
        int d = edst[e];
        int p = off[d] + atomicAdd(&cursor[d], 1);
        srcs[p] = esrc[e];
    }
}

// ---------------------------------------------------------------- PQ = h @ [Wtop | Wbot] (+bias on Q)
__global__ __launch_bounds__(256) void gemm_pq_kernel(
    const short* __restrict__ hbf, const short* __restrict__ wpreT2,
    const float* __restrict__ bpre, short* __restrict__ PQ)
{
    __shared__ __align__(16) short As[128][72];
    __shared__ __align__(16) short Bs[256][72];

    const int tid = threadIdx.x;
    const int bn = blockIdx.x * 128;
    const int lane = tid & 63, wv = tid >> 6;
    const int lm = lane & 15, quad = lane >> 4;

    f32x4 acc[2][16];
#pragma unroll
    for (int a = 0; a < 2; a++)
#pragma unroll
        for (int b = 0; b < 16; b++) acc[a][b] = (f32x4){0.f, 0.f, 0.f, 0.f};

#pragma unroll
    for (int kc = 0; kc < 2; kc++) {
        __syncthreads();
#pragma unroll
        for (int t = 0; t < 4; t++) {
            int q = tid + t * 256;
            int m = q >> 3, seg = q & 7;
            int n = bn + m; if (n >= N_NODES) n = N_NODES - 1;
            *(int4*)&As[m][seg * 8] = *(const int4*)(hbf + (long)n * 128 + kc * 64 + seg * 8);
        }
#pragma unroll
        for (int t = 0; t < 8; t++) {
            int q = tid + t * 256;
            int n = q >> 3, seg = q & 7;
            *(int4*)&Bs[n][seg * 8] = *(const int4*)(wpreT2 + n * 128 + kc * 64 + seg * 8);
        }
        __syncthreads();
#pragma unroll
        for (int ks = 0; ks < 2; ks++) {
            const int ko = ks * 32 + quad * 8;
            bf16x8 a0 = *(const bf16x8*)&As[wv * 32 + lm][ko];
            bf16x8 a1 = *(const bf16x8*)&As[wv * 32 + 16 + lm][ko];
#pragma unroll
            for (int ct = 0; ct < 16; ct++) {
                bf16x8 b = *(const bf16x8*)&Bs[ct * 16 + lm][ko];
                acc[0][ct] = __builtin_amdgcn_mfma_f32_16x16x32_bf16(b, a0, acc[0][ct], 0, 0, 0);
                acc[1][ct] = __builtin_amdgcn_mfma_f32_16x16x32_bf16(b, a1, acc[1][ct], 0, 0, 0);
            }
        }
    }

    // epilogue: row = node, col 0-127 = P (no bias), 128-255 = Q (+bias)
#pragma unroll
    for (int rt = 0; rt < 2; rt++) {
        int row = wv * 32 + rt * 16 + lm;
        int n = bn + row;
        if (n >= N_NODES) continue;
        short* dst = PQ + (long)n * 256;
#pragma unroll
        for (int ct = 0; ct < 16; ct++) {
            int col = ct * 16 + quad * 4;
            float v0 = acc[rt][ct][0], v1 = acc[rt][ct][1], v2 = acc[rt][ct][2], v3 = acc[rt][ct][3];
            if (ct >= 8) {
                float4 bv = *(const float4*)(bpre + (col - 128));
                v0 += bv.x; v1 += bv.y; v2 += bv.z; v3 += bv.w;
            }
            int2 pkd; pkd.x = (int)pk2(v0, v1); pkd.y = (int)pk2(v2, v3);
            *(int2*)(dst + col) = pkd;
        }
    }
}

// ---------------------------------------------------------------- fused edge compute + stats: one wave per node
__global__ __launch_bounds__(256) void edgestats_kernel(
    const short* __restrict__ PQ, const int* __restrict__ srcs,
    const int* __restrict__ off, short* __restrict__ aggbf)
{
    const int wv = threadIdx.x >> 6, lane = threadIdx.x & 63;
    const int n = blockIdx.x * 4 + wv;            // grid 12500 * 4 waves = 50000
    const unsigned* Pb = (const unsigned*)PQ;     // u32 view: row = 128 u32 (P=0..63, Q=64..127)

    const int s0 = __builtin_amdgcn_readfirstlane(off[n]);
    const int s1 = __builtin_amdgcn_readfirstlane(off[n + 1]);

    unsigned qu = Pb[(long)n * 128 + 64 + lane];
    const float qa = blo(qu), qb = bhi(qu);

    float sA = 0.f, sB = 0.f, qA = 0.f, qB = 0.f;
    float mxA = -1e30f, mxB = -1e30f, mnA = 1e30f, mnB = 1e30f;

    int p = s0;
    for (; p + 4 <= s1; p += 4) {
        int i0 = srcs[p], i1 = srcs[p + 1], i2 = srcs[p + 2], i3 = srcs[p + 3];
        unsigned u0 = Pb[(long)i0 * 128 + lane];
        unsigned u1 = Pb[(long)i1 * 128 + lane];
        unsigned u2 = Pb[(long)i2 * 128 + lane];
        unsigned u3 = Pb[(long)i3 * 128 + lane];
#pragma unroll
        for (int j = 0; j < 4; j++) {
            unsigned u = (j == 0) ? u0 : (j == 1) ? u1 : (j == 2) ? u2 : u3;
            float a = blo(u) + qa; a = a > 0.f ? a : 0.f;
            float b = bhi(u) + qb; b = b > 0.f ? b : 0.f;
            sA += a; sB += b; qA += a * a; qB += b * b;
            mxA = fmaxf(mxA, a); mxB = fmaxf(mxB, b);
            mnA = fminf(mnA, a); mnB = fminf(mnB, b);
        }
    }
    for (; p < s1; p++) {
        unsigned u = Pb[(long)srcs[p] * 128 + lane];
        float a = blo(u) + qa; a = a > 0.f ? a : 0.f;
        float b = bhi(u) + qb; b = b > 0.f ? b : 0.f;
        sA += a; sB += b; qA += a * a; qB += b * b;
        mxA = fmaxf(mxA, a); mxB = fmaxf(mxB, b);
        mnA = fminf(mnA, a); mnB = fminf(mnB, b);
    }

    float inv = 1.0f / (float)(s1 - s0);   // deg >= 1 guaranteed (self-loops)
    float mA = sA * inv, mB = sB * inv;
    float vA = qA * inv - mA * mA; vA = vA > 0.f ? vA : 0.f;
    float vB = qB * inv - mB * mB; vB = vB > 0.f ? vB : 0.f;
    float stA = sqrtf(vA + EPS_V), stB = sqrtf(vB + EPS_V);

    unsigned* ag = (unsigned*)(aggbf + (long)n * 512);
    ag[lane]       = pk2(mA, mB);
    ag[64 + lane]  = pk2(mxA, mxB);
    ag[128 + lane] = pk2(mnA, mnB);
    ag[192 + lane] = pk2(stA, stB);
}

// ---------------------------------------------------------------- fused post + mix per node
__global__ __launch_bounds__(256) void node_kernel(
    const float* __restrict__ h, const short* __restrict__ hbf, const short* __restrict__ aggbf,
    const int* __restrict__ degc, const short* __restrict__ wpostT, const float* __restrict__ bpost,
    const short* __restrict__ wmixT, const float* __restrict__ bmix, float* __restrict__ out)
{
    __shared__ __align__(16) short As[128][72];
    __shared__ __align__(16) short Bs[128][72];
    __shared__ float sAmp[128], sAtt[128];

    const int tid = threadIdx.x;
    const int bn = blockIdx.x * 128;
    if (tid < 128) {
        int n = bn + tid; if (n >= N_NODES) n = N_NODES - 1;
        float d = (float)degc[n];
        float ld = logf(d + 1.0f);
        sAmp[tid] = ld * (1.0f / AVG_D_LOG);
        sAtt[tid] = AVG_D_LOG / ld;
    }
    __syncthreads();

    const int lane = tid & 63, wv = tid >> 6;
    const int lm = lane & 15, quad = lane >> 4;

    f32x4 acc[2][8];
#pragma unroll
    for (int a = 0; a < 2; a++)
#pragma unroll
        for (int b = 0; b < 8; b++) acc[a][b] = (f32x4){0.f, 0.f, 0.f, 0.f};

    // ---- post GEMM: K = 1664 = 26 chunks of 64
    for (int c = 0; c < 26; c++) {
        __syncthreads();
        const int r = c >> 1;
        const int half = (c & 1) * 64;
#pragma unroll
        for (int t = 0; t < 4; t++) {
            int q = tid + t * 256;
            int m = q >> 3, seg = q & 7;
            int n = bn + m; if (n >= N_NODES) n = N_NODES - 1;
            int4 v;
            if (r == 0) {
                v = *(const int4*)(hbf + (long)n * 128 + half + seg * 8);
            } else {
                int a = (r - 1) & 3, s = (r - 1) >> 2;
                v = *(const int4*)(aggbf + (long)n * 512 + a * 128 + half + seg * 8);
                if (s) {
                    float sc = (s == 1) ? sAmp[m] : sAtt[m];
                    unsigned* pu = (unsigned*)&v;
#pragma unroll
                    for (int j = 0; j < 4; j++) {
                        unsigned u = pu[j];
                        pu[j] = pk2(blo(u) * sc, bhi(u) * sc);
                    }
                }
            }
            *(int4*)&As[m][seg * 8] = v;
        }
#pragma unroll
        for (int t = 0; t < 4; t++) {
            int q = tid + t * 256;
            int n = q >> 3, seg = q & 7;
            *(int4*)&Bs[n][seg * 8] = *(const int4*)(wpostT + n * 1664 + c * 64 + seg * 8);
        }
        __syncthreads();
#pragma unroll
        for (int ks = 0; ks < 2; ks++) {
            const int ko = ks * 32 + quad * 8;
            bf16x8 a0 = *(const bf16x8*)&As[wv * 32 + lm][ko];
            bf16x8 a1 = *(const bf16x8*)&As[wv * 32 + 16 + lm][ko];
#pragma unroll
            for (int ct = 0; ct < 8; ct++) {
                bf16x8 b = *(const bf16x8*)&Bs[ct * 16 + lm][ko];
                acc[0][ct] = __builtin_amdgcn_mfma_f32_16x16x32_bf16(b, a0, acc[0][ct], 0, 0, 0);
                acc[1][ct] = __builtin_amdgcn_mfma_f32_16x16x32_bf16(b, a1, acc[1][ct], 0, 0, 0);
            }
        }
    }

    // hp = relu(acc + b_post)
#pragma unroll
    for (int rt = 0; rt < 2; rt++)
#pragma unroll
        for (int ct = 0; ct < 8; ct++) {
            float4 bv = *(const float4*)(bpost + ct * 16 + quad * 4);
            float v0 = acc[rt][ct][0] + bv.x; acc[rt][ct][0] = v0 > 0.f ? v0 : 0.f;
            float v1 = acc[rt][ct][1] + bv.y; acc[rt][ct][1] = v1 > 0.f ? v1 : 0.f;
            float v2 = acc[rt][ct][2] + bv.z; acc[rt][ct][2] = v2 > 0.f ? v2 : 0.f;
            float v3 = acc[rt][ct][3] + bv.w; acc[rt][ct][3] = v3 > 0.f ? v3 : 0.f;
        }

    // ---- mix GEMM: K = 128
    f32x4 acc2[2][8];
#pragma unroll
    for (int a = 0; a < 2; a++)
#pragma unroll
        for (int b = 0; b < 8; b++) acc2[a][b] = (f32x4){0.f, 0.f, 0.f, 0.f};

#pragma unroll
    for (int kc = 0; kc < 2; kc++) {
        __syncthreads();
#pragma unroll
        for (int ctl = 0; ctl < 4; ctl++) {
            int ct = kc * 4 + ctl;
#pragma unroll
            for (int rt = 0; rt < 2; rt++) {
                int row = wv * 32 + rt * 16 + lm;
                int col = ctl * 16 + quad * 4;
                int2 pkd;
                pkd.x = (int)pk2(acc[rt][ct][0], acc[rt][ct][1]);
                pkd.y = (int)pk2(acc[rt][ct][2], acc[rt][ct][3]);
                *(int2*)&As[row][col] = pkd;
            }
        }
#pragma unroll
        for (int t = 0; t < 4; t++) {
            int q = tid + t * 256;
            int n = q >> 3, seg = q & 7;
            *(int4*)&Bs[n][seg * 8] = *(const int4*)(wmixT + n * 128 + kc * 64 + seg * 8);
        }
        __syncthreads();
#pragma unroll
        for (int ks = 0; ks < 2; ks++) {
            const int ko = ks * 32 + quad * 8;
            bf16x8 a0 = *(const bf16x8*)&As[wv * 32 + lm][ko];
            bf16x8 a1 = *(const bf16x8*)&As[wv * 32 + 16 + lm][ko];
#pragma unroll
            for (int ct = 0; ct < 8; ct++) {
                bf16x8 b = *(const bf16x8*)&Bs[ct * 16 + lm][ko];
                acc2[0][ct] = __builtin_amdgcn_mfma_f32_16x16x32_bf16(b, a0, acc2[0][ct], 0, 0, 0);
                acc2[1][ct] = __builtin_amdgcn_mfma_f32_16x16x32_bf16(b, a1, acc2[1][ct], 0, 0, 0);
            }
        }
    }

    // epilogue: out = h + leaky_relu(acc2 + b_mix)
#pragma unroll
    for (int rt = 0; rt < 2; rt++) {
        int row = wv * 32 + rt * 16 + lm;
        int n = bn + row;
        if (n >= N_NODES) continue;
#pragma unroll
        for (int ct = 0; ct < 8; ct++) {
            int col = ct * 16 + quad * 4;
            float4 bv = *(const float4*)(bmix + col);
            float4 hv = *(const float4*)(h + (long)n * 128 + col);
            float4 o;
            float v0 = acc2[rt][ct][0] + bv.x; v0 = v0 > 0.f ? v0 : 0.01f * v0; o.x = hv.x + v0;
            float v1 = acc2[rt][ct][1] + bv.y; v1 = v1 > 0.f ? v1 : 0.01f * v1; o.y = hv.y + v1;
            float v2 = acc2[rt][ct][2] + bv.z; v2 = v2 > 0.f ? v2 : 0.01f * v2; o.z = hv.z + v2;
            float v3 = acc2[rt][ct][3] + bv.w; v3 = v3 > 0.f ? v3 : 0.01f * v3; o.w = hv.w + v3;
            *(float4*)(out + (long)n * 128 + col) = o;
        }
    }
}

extern "C" void kernel_launch(void* const* d_in, const int* in_sizes, int n_in,
                              void* d_out, int out_size, void* d_ws, size_t ws_size,
                              hipStream_t stream) {
    const float* h     = (const float*)d_in[0];
    const int*   esrc  = (const int*)d_in[1];
    const int*   edst  = (const int*)d_in[2];
    const float* Wpre  = (const float*)d_in[3];
    const float* bpre  = (const float*)d_in[4];
    const float* Wpost = (const float*)d_in[5];
    const float* bpost = (const float*)d_in[6];
    const float* Wmix  = (const float*)d_in[7];
    const float* bmix  = (const float*)d_in[8];
    float* out = (float*)d_out;
    char* ws = (char*)d_ws;

    short* PQ     = (short*)(ws + PQ_B);
    short* aggbf  = (short*)(ws + AGG_B);
    short* hbf    = (short*)(ws + HBF_B);
    short* wpreT2 = (short*)(ws + WPRET2_B);
    short* wpostT = (short*)(ws + WPOSTT_B);
    short* wmixT  = (short*)(ws + WMIXT_B);
    int*   degc   = (int*)(ws + DEGC_B);
    int*   off    = (int*)(ws + OFF_B);
    int*   cursor = (int*)(ws + CUR_B);
    int*   srcs   = (int*)(ws + SRCS_B);
    int*   bsum   = (int*)(ws + BSUM_B);

    prep_kernel<<<26415, 256, 0, stream>>>(h, Wpre, Wpost, Wmix, hbf, wpreT2, wpostT, wmixT, degc, cursor);
    hist_kernel<<<(N_EDGES + 255) / 256, 256, 0, stream>>>(edst, degc);
    scan1_kernel<<<NB_SCAN, 256, 0, stream>>>(degc, bsum);
    scan2_kernel<<<1, 64, 0, stream>>>(bsum, off);
    scan3_kernel<<<NB_SCAN, 256, 0, stream>>>(degc, bsum, off);
    scatter_kernel<<<(N_EDGES + 255) / 256, 256, 0, stream>>>(esrc, edst, off, cursor, srcs);
    gemm_pq_kernel<<<(N_NODES + 127) / 128, 256, 0, stream>>>(hbf, wpreT2, bpre, PQ);
    edgestats_kernel<<<N_NODES / 4, 256, 0, stream>>>(PQ, srcs, off, aggbf);
    node_kernel<<<(N_NODES + 127) / 128, 256, 0, stream>>>(h, hbf, aggbf, degc, wpostT, bpost, wmixT, bmix, out);
}